// Round 5
// baseline (709.817 us; speedup 1.0000x reference)
//
#include <hip/hip_runtime.h>
#include <stdint.h>

typedef unsigned short u16;
typedef unsigned int u32;
typedef __attribute__((ext_vector_type(4))) float f32x4;
typedef __attribute__((ext_vector_type(8))) short bf16x8;

#define NB 128      // graphs
#define LL 256      // nodes per graph
#define DD 128      // hidden
#define EDGES 524288
#define EPG 4096    // edges per graph
#define NN (NB*LL)

__device__ __forceinline__ float bf2f(u16 u) {
    union { u32 i; float f; } v; v.i = ((u32)u) << 16; return v.f;
}
__device__ __forceinline__ u16 f2bf(float f) {
    union { float f; u32 i; } v; v.f = f;
    u32 i = v.i;
    u32 r = (i + 0x7fffu + ((i >> 16) & 1u)) >> 16;   // RNE
    return (u16)r;
}
__device__ __forceinline__ float matfn(float a, float dv) {
    if (a != 0.f) return (a == 1.2f) ? 1.1f : a;
    return (dv == 0.f) ? 0.f : exp2f((1.f - dv) * 0.5849625007211562f); // 1.5^(1-dis)
}
__device__ __forceinline__ float red16(float v) {
#pragma unroll
    for (int off = 1; off < 16; off <<= 1) v += __shfl_xor(v, off, 64);
    return v;
}

// ---------------- prep kernels ----------------

__global__ __launch_bounds__(256) void build_matrix_k(const float* __restrict__ adj,
                                                      const float* __restrict__ dis,
                                                      float* __restrict__ mat, int n) {
    int i = blockIdx.x * 256 + threadIdx.x;
    if (i >= n) return;
    mat[i] = matfn(adj[i], dis[i]);
}

__global__ __launch_bounds__(256) void zero_f32(float* __restrict__ p, int n) {
    int i = blockIdx.x * 256 + threadIdx.x;
    if (i < n) p[i] = 0.f;
}

__global__ __launch_bounds__(256) void scatter_w_k(const int* __restrict__ srcI,
                                                   const int* __restrict__ dstI,
                                                   const float* __restrict__ ew,
                                                   float* __restrict__ Wf) {
    int e = blockIdx.x * 256 + threadIdx.x;
    if (e >= EDGES) return;
    int b = e >> 12;
    atomicAdd(&Wf[(size_t)b * 65536 + (size_t)(dstI[e] & 255) * 256 + (srcI[e] & 255)], ew[e]);
}

__global__ __launch_bounds__(256) void cast_w_k(const float* __restrict__ Wf, u16* __restrict__ Wb) {
    int i = blockIdx.x * 256 + threadIdx.x;
    float4 v = ((const float4*)Wf)[i];
    ushort4 o;
    o.x = f2bf(v.x); o.y = f2bf(v.y); o.z = f2bf(v.z); o.w = f2bf(v.w);
    ((ushort4*)Wb)[i] = o;
}

__global__ __launch_bounds__(256) void build_wconvT0_k(const float* __restrict__ rel,
                                                       const float* __restrict__ root,
                                                       u16* __restrict__ dst) {
    int i = blockIdx.x * 256 + threadIdx.x;   // 128*128
    int m = i >> 7, k = i & 127;
    float v = 0.f;
    if (k < 40) v = rel[k * 128 + m];
    else if (k >= 64 && k < 104) v = root[(k - 64) * 128 + m];
    dst[m * 128 + k] = f2bf(v);
}

__global__ __launch_bounds__(256) void build_wconvT_k(const float* __restrict__ rel,
                                                      const float* __restrict__ root,
                                                      u16* __restrict__ dst) {
    int i = blockIdx.x * 256 + threadIdx.x;   // 128*256
    int m = i >> 8, k = i & 255;
    float v = (k < 128) ? rel[k * 128 + m] : root[(k - 128) * 128 + m];
    dst[m * 256 + k] = f2bf(v);
}

__global__ __launch_bounds__(256) void build_wqkvT_k(const float* __restrict__ wq,
                                                     const float* __restrict__ wk,
                                                     const float* __restrict__ wv,
                                                     u16* __restrict__ dst) {
    int i = blockIdx.x * 256 + threadIdx.x;   // 768*128
    int m = i >> 7, k = i & 127;
    const float* s = (m < 256) ? wq : (m < 512) ? wk : wv;
    int mm = m & 255;
    dst[m * 128 + k] = f2bf(s[k * 256 + mm]);
}

__global__ __launch_bounds__(256) void transpose_cast_k(const float* __restrict__ src,
                                                        u16* __restrict__ dst, int K, int M) {
    int i = blockIdx.x * 256 + threadIdx.x;
    if (i >= K * M) return;
    int m = i / K, k = i - m * K;
    dst[i] = f2bf(src[k * M + m]);   // dst [M][K]
}

// per-graph transpose: h [N,128] bf16 (or x [N,40] f32, zero-padded) -> hT [b][128][256]
template<bool IS0>
__global__ __launch_bounds__(256) void transpose_h_k(const u16* __restrict__ h,
                                                     const float* __restrict__ x,
                                                     u16* __restrict__ hT) {
    int gw = blockIdx.x * 4 + (threadIdx.x >> 6);
    int lane = threadIdx.x & 63;
    int b = gw >> 6, rem = gw & 63, db = rem >> 5, jb = rem & 31;
    int d = (db << 6) + lane;
    u16 vals[8];
#pragma unroll
    for (int jj = 0; jj < 8; ++jj) {
        int node = (b << 8) + (jb << 3) + jj;
        if (IS0) vals[jj] = (d < 40) ? f2bf(x[(size_t)node * 40 + d]) : (u16)0;
        else     vals[jj] = h[(size_t)node * 128 + d];
    }
    *(uint4*)(hT + (size_t)b * 32768 + (size_t)d * 256 + (jb << 3)) = *(uint4*)vals;
}

// per-(b,h) V transpose: qkv V-section [node][64] -> vT [b*4+h][64][256]
__global__ __launch_bounds__(256) void vT_k(const u16* __restrict__ qkv, u16* __restrict__ vT) {
    __shared__ __align__(16) u16 vt[64][264];
    int bh = blockIdx.x;
    int b = bh >> 2, hh = bh & 3;
    int t = threadIdx.x;
    const u16* base = qkv + (size_t)b * 256 * 768 + 512 + hh * 64;
#pragma unroll
    for (int rep = 0; rep < 8; ++rep) {
        int idx = rep * 256 + t;
        int node = idx >> 3, oct = idx & 7;
        uint4 val = *(const uint4*)(base + (size_t)node * 768 + oct * 8);
        const u16* pv = (const u16*)&val;
#pragma unroll
        for (int j = 0; j < 8; ++j) vt[oct * 8 + j][node] = pv[j];
    }
    __syncthreads();
    u16* out = vT + (size_t)bh * 16384;
#pragma unroll
    for (int rep = 0; rep < 8; ++rep) {
        int idx = rep * 256 + t;
        int d = idx >> 5, gq = idx & 31;
        u16 tmp[8];
#pragma unroll
        for (int j = 0; j < 8; ++j) tmp[j] = vt[d][gq * 8 + j];
        *(uint4*)(out + d * 256 + gq * 8) = *(uint4*)tmp;
    }
}

// ---------------- per-graph aggregation GEMM: Acat = [W@h | h]  (K=256) ----------------

template<bool IS0>
__global__ __launch_bounds__(256) void gemm_agg(const u16* __restrict__ Wb,
                                                const u16* __restrict__ BT0,
                                                const u16* __restrict__ h,
                                                const float* __restrict__ x,
                                                u16* __restrict__ Acat) {
    __shared__ __align__(16) u16 lds[8192];
    char* ldsc = (char*)lds;
    int t = threadIdx.x, lane = t & 63, wid = t >> 6;
    int b = blockIdx.x >> 1, rt = blockIdx.x & 1;
    int row0 = rt << 7, nbase = b << 8;
    const u16* A = Wb + (size_t)b * 65536 + (size_t)row0 * 256;
    const u16* BT = BT0 + (size_t)b * 32768;

    f32x4 zero = {0.f, 0.f, 0.f, 0.f};
    f32x4 acc[4][4];
#pragma unroll
    for (int mt = 0; mt < 4; ++mt)
#pragma unroll
        for (int nt = 0; nt < 4; ++nt) acc[mt][nt] = zero;

    int wr = wid >> 1, wc = wid & 1;
    int rA = wr * 64 + (lane & 15);
    int rB = wc * 64 + (lane & 15);
    int kch = (lane >> 4) << 4;

    for (int kt = 0; kt < 8; ++kt) {
        int kc = kt << 5;
#pragma unroll
        for (int i = 0; i < 2; ++i) {
            int off = wid * 2048 + i * 1024 + lane * 16;
            int r = off >> 6, cb = off & 63;
            __builtin_amdgcn_global_load_lds((const u32*)((const char*)A + ((size_t)r * 256 + kc) * 2 + cb),
                                             (u32*)(ldsc + wid * 2048 + i * 1024), 16, 0, 0);
            __builtin_amdgcn_global_load_lds((const u32*)((const char*)BT + ((size_t)r * 256 + kc) * 2 + cb),
                                             (u32*)(ldsc + 8192 + wid * 2048 + i * 1024), 16, 0, 0);
        }
        __syncthreads();
        bf16x8 af[4], bfr[4];
#pragma unroll
        for (int mt = 0; mt < 4; ++mt)
            af[mt] = *(const bf16x8*)(ldsc + (rA + mt * 16) * 64 + kch);
#pragma unroll
        for (int nt = 0; nt < 4; ++nt)
            bfr[nt] = *(const bf16x8*)(ldsc + 8192 + (rB + nt * 16) * 64 + kch);
#pragma unroll
        for (int mt = 0; mt < 4; ++mt)
#pragma unroll
            for (int nt = 0; nt < 4; ++nt)
                acc[mt][nt] = __builtin_amdgcn_mfma_f32_16x16x32_bf16(af[mt], bfr[nt], acc[mt][nt], 0, 0, 0);
        __syncthreads();
    }

    int colb = wc * 64 + (lane & 15);
    int rowb = wr * 64 + ((lane >> 4) << 2);
#pragma unroll
    for (int mt = 0; mt < 4; ++mt)
#pragma unroll
        for (int nt = 0; nt < 4; ++nt)
#pragma unroll
            for (int r = 0; r < 4; ++r) {
                int i = rowb + mt * 16 + r;
                int c = colb + nt * 16;
                float v = acc[mt][nt][r];
                if (IS0) Acat[(size_t)(nbase + row0 + i) * 128 + c] = f2bf(v);
                else     Acat[(size_t)(nbase + row0 + i) * 256 + c] = f2bf(v);
            }
    if (IS0) {
        for (int idx = t; idx < 128 * 40; idx += 256) {
            int i = idx / 40, c = idx - i * 40;
            int node = nbase + row0 + i;
            Acat[(size_t)node * 128 + 64 + c] = f2bf(x[(size_t)node * 40 + c]);
        }
    } else {
        for (int idx = t; idx < 2048; idx += 256) {
            int i = idx >> 4, q = idx & 15;
            int node = nbase + row0 + i;
            *(uint4*)(Acat + (size_t)node * 256 + 128 + (q << 3)) =
                *(const uint4*)(h + (size_t)node * 128 + (q << 3));
        }
    }
}

// ---------------- generic bf16 GEMM (qkv, proj) ----------------
// OUTMODE: 1 = bf16 store, 2 = f32 store + f32 bias

template<int OUTMODE>
__global__ __launch_bounds__(256) void gemm_bt(const u16* __restrict__ A,
                                               const u16* __restrict__ BT,
                                               void* __restrict__ Out,
                                               const float* __restrict__ bias,
                                               int K, int Mtot) {
    __shared__ __align__(16) u16 lds[8192];
    char* ldsc = (char*)lds;
    int t = threadIdx.x, lane = t & 63, wid = t >> 6;
    int row0 = blockIdx.x * 128, col0 = blockIdx.y * 128;

    f32x4 zero = {0.f, 0.f, 0.f, 0.f};
    f32x4 acc[4][4];
#pragma unroll
    for (int mt = 0; mt < 4; ++mt)
#pragma unroll
        for (int nt = 0; nt < 4; ++nt) acc[mt][nt] = zero;

    int nk = K >> 5;
    int wr = wid >> 1, wc = wid & 1;
    int rA = wr * 64 + (lane & 15);
    int rB = wc * 64 + (lane & 15);
    int kch = (lane >> 4) << 4;

    for (int kt = 0; kt < nk; ++kt) {
        int kc = kt << 5;
#pragma unroll
        for (int i = 0; i < 2; ++i) {
            int off = wid * 2048 + i * 1024 + lane * 16;
            int r = off >> 6, cb = off & 63;
            __builtin_amdgcn_global_load_lds((const u32*)((const char*)A + ((size_t)(row0 + r) * K + kc) * 2 + cb),
                                             (u32*)(ldsc + wid * 2048 + i * 1024), 16, 0, 0);
            __builtin_amdgcn_global_load_lds((const u32*)((const char*)BT + ((size_t)(col0 + r) * K + kc) * 2 + cb),
                                             (u32*)(ldsc + 8192 + wid * 2048 + i * 1024), 16, 0, 0);
        }
        __syncthreads();
        bf16x8 af[4], bfr[4];
#pragma unroll
        for (int mt = 0; mt < 4; ++mt)
            af[mt] = *(const bf16x8*)(ldsc + (rA + mt * 16) * 64 + kch);
#pragma unroll
        for (int nt = 0; nt < 4; ++nt)
            bfr[nt] = *(const bf16x8*)(ldsc + 8192 + (rB + nt * 16) * 64 + kch);
#pragma unroll
        for (int mt = 0; mt < 4; ++mt)
#pragma unroll
            for (int nt = 0; nt < 4; ++nt)
                acc[mt][nt] = __builtin_amdgcn_mfma_f32_16x16x32_bf16(af[mt], bfr[nt], acc[mt][nt], 0, 0, 0);
        __syncthreads();
    }

    int colb = col0 + wc * 64 + (lane & 15);
    int rowb = row0 + wr * 64 + ((lane >> 4) << 2);
#pragma unroll
    for (int mt = 0; mt < 4; ++mt)
#pragma unroll
        for (int nt = 0; nt < 4; ++nt)
#pragma unroll
            for (int r = 0; r < 4; ++r) {
                int row = rowb + mt * 16 + r;
                int c = colb + nt * 16;
                float v = acc[mt][nt][r];
                if (OUTMODE == 1) ((u16*)Out)[(size_t)row * Mtot + c] = f2bf(v);
                else ((float*)Out)[(size_t)row * Mtot + c] = v + bias[c];
            }
}

// ---------------- conv GEMM with fused bias + LN + relu (Mtot = 128 full width) ----------------

template<int KK>
__global__ __launch_bounds__(256) void gemm_conv_ln(const u16* __restrict__ A,
                                                    const u16* __restrict__ BT,
                                                    const float* __restrict__ rb,
                                                    const float* __restrict__ g,
                                                    const float* __restrict__ be,
                                                    u16* __restrict__ hout) {
    __shared__ __align__(16) u16 lds[8192];
    char* ldsc = (char*)lds;
    int t = threadIdx.x, lane = t & 63, wid = t >> 6;
    int row0 = blockIdx.x * 128;

    f32x4 zero = {0.f, 0.f, 0.f, 0.f};
    f32x4 acc[4][4];
#pragma unroll
    for (int mt = 0; mt < 4; ++mt)
#pragma unroll
        for (int nt = 0; nt < 4; ++nt) acc[mt][nt] = zero;

    int wr = wid >> 1, wc = wid & 1;
    int rA = wr * 64 + (lane & 15);
    int rB = wc * 64 + (lane & 15);
    int kch = (lane >> 4) << 4;

    for (int kt = 0; kt < (KK >> 5); ++kt) {
        int kc = kt << 5;
#pragma unroll
        for (int i = 0; i < 2; ++i) {
            int off = wid * 2048 + i * 1024 + lane * 16;
            int r = off >> 6, cb = off & 63;
            __builtin_amdgcn_global_load_lds((const u32*)((const char*)A + ((size_t)(row0 + r) * KK + kc) * 2 + cb),
                                             (u32*)(ldsc + wid * 2048 + i * 1024), 16, 0, 0);
            __builtin_amdgcn_global_load_lds((const u32*)((const char*)BT + ((size_t)r * KK + kc) * 2 + cb),
                                             (u32*)(ldsc + 8192 + wid * 2048 + i * 1024), 16, 0, 0);
        }
        __syncthreads();
        bf16x8 af[4], bfr[4];
#pragma unroll
        for (int mt = 0; mt < 4; ++mt)
            af[mt] = *(const bf16x8*)(ldsc + (rA + mt * 16) * 64 + kch);
#pragma unroll
        for (int nt = 0; nt < 4; ++nt)
            bfr[nt] = *(const bf16x8*)(ldsc + 8192 + (rB + nt * 16) * 64 + kch);
#pragma unroll
        for (int mt = 0; mt < 4; ++mt)
#pragma unroll
            for (int nt = 0; nt < 4; ++nt)
                acc[mt][nt] = __builtin_amdgcn_mfma_f32_16x16x32_bf16(af[mt], bfr[nt], acc[mt][nt], 0, 0, 0);
        __syncthreads();
    }

    float* redS = (float*)ldsc;            // [128][2]
    float* redQ = (float*)(ldsc + 2048);   // [128][2]
    int colbase = wc * 64 + (lane & 15);
    int qrow = (lane >> 4) << 2;
    float rbv[4], gv[4], bev[4];
#pragma unroll
    for (int nt = 0; nt < 4; ++nt) {
        int c = colbase + nt * 16;
        rbv[nt] = rb[c]; gv[nt] = g[c]; bev[nt] = be[c];
    }
#pragma unroll
    for (int mt = 0; mt < 4; ++mt)
#pragma unroll
        for (int r = 0; r < 4; ++r) {
            float s = 0.f, q = 0.f;
#pragma unroll
            for (int nt = 0; nt < 4; ++nt) {
                float v = acc[mt][nt][r] + rbv[nt];
                s += v; q += v * v;
            }
            s = red16(s); q = red16(q);
            if ((lane & 15) == 0) {
                int lr = wr * 64 + qrow + mt * 16 + r;
                redS[lr * 2 + wc] = s; redQ[lr * 2 + wc] = q;
            }
        }
    __syncthreads();
#pragma unroll
    for (int mt = 0; mt < 4; ++mt)
#pragma unroll
        for (int r = 0; r < 4; ++r) {
            int lr = wr * 64 + qrow + mt * 16 + r;
            float mu = (redS[lr * 2] + redS[lr * 2 + 1]) * (1.f / 128.f);
            float var = (redQ[lr * 2] + redQ[lr * 2 + 1]) * (1.f / 128.f) - mu * mu;
            float rs = rsqrtf(var + 1e-5f);
            size_t rbase = (size_t)(row0 + lr) * 128;
#pragma unroll
            for (int nt = 0; nt < 4; ++nt) {
                float v = acc[mt][nt][r] + rbv[nt];
                float o = (v - mu) * rs * gv[nt] + bev[nt];
                o = o < 0.f ? 0.f : o;
                hout[rbase + colbase + nt * 16] = f2bf(o);
            }
        }
}

// ---------------- fc GEMM with fused LN -> +residual -> LN (K=256, Mtot=128) ----------------

__global__ __launch_bounds__(256) void gemm_fc_ln2(const u16* __restrict__ A,
                                                   const u16* __restrict__ BT,
                                                   const float* __restrict__ mg,
                                                   const float* __restrict__ mb,
                                                   const float* __restrict__ eg,
                                                   const float* __restrict__ eb,
                                                   u16* __restrict__ h) {
    __shared__ __align__(16) u16 lds[8192];
    char* ldsc = (char*)lds;
    int t = threadIdx.x, lane = t & 63, wid = t >> 6;
    int row0 = blockIdx.x * 128;

    f32x4 zero = {0.f, 0.f, 0.f, 0.f};
    f32x4 acc[4][4];
#pragma unroll
    for (int mt = 0; mt < 4; ++mt)
#pragma unroll
        for (int nt = 0; nt < 4; ++nt) acc[mt][nt] = zero;

    int wr = wid >> 1, wc = wid & 1;
    int rA = wr * 64 + (lane & 15);
    int rB = wc * 64 + (lane & 15);
    int kch = (lane >> 4) << 4;

    for (int kt = 0; kt < 8; ++kt) {
        int kc = kt << 5;
#pragma unroll
        for (int i = 0; i < 2; ++i) {
            int off = wid * 2048 + i * 1024 + lane * 16;
            int r = off >> 6, cb = off & 63;
            __builtin_amdgcn_global_load_lds((const u32*)((const char*)A + ((size_t)(row0 + r) * 256 + kc) * 2 + cb),
                                             (u32*)(ldsc + wid * 2048 + i * 1024), 16, 0, 0);
            __builtin_amdgcn_global_load_lds((const u32*)((const char*)BT + ((size_t)r * 256 + kc) * 2 + cb),
                                             (u32*)(ldsc + 8192 + wid * 2048 + i * 1024), 16, 0, 0);
        }
        __syncthreads();
        bf16x8 af[4], bfr[4];
#pragma unroll
        for (int mt = 0; mt < 4; ++mt)
            af[mt] = *(const bf16x8*)(ldsc + (rA + mt * 16) * 64 + kch);
#pragma unroll
        for (int nt = 0; nt < 4; ++nt)
            bfr[nt] = *(const bf16x8*)(ldsc + 8192 + (rB + nt * 16) * 64 + kch);
#pragma unroll
        for (int mt = 0; mt < 4; ++mt)
#pragma unroll
            for (int nt = 0; nt < 4; ++nt)
                acc[mt][nt] = __builtin_amdgcn_mfma_f32_16x16x32_bf16(af[mt], bfr[nt], acc[mt][nt], 0, 0, 0);
        __syncthreads();
    }

    float* redS  = (float*)ldsc;
    float* redQ  = (float*)(ldsc + 2048);
    float* redS2 = (float*)(ldsc + 4096);
    float* redQ2 = (float*)(ldsc + 6144);
    int colbase = wc * 64 + (lane & 15);
    int qrow = (lane >> 4) << 2;
    float mgv[4], mbv[4], egv[4], ebv[4];
#pragma unroll
    for (int nt = 0; nt < 4; ++nt) {
        int c = colbase + nt * 16;
        mgv[nt] = mg[c]; mbv[nt] = mb[c]; egv[nt] = eg[c]; ebv[nt] = eb[c];
    }
    // round 1: LN over fc output
#pragma unroll
    for (int mt = 0; mt < 4; ++mt)
#pragma unroll
        for (int r = 0; r < 4; ++r) {
            float s = 0.f, q = 0.f;
#pragma unroll
            for (int nt = 0; nt < 4; ++nt) {
                float v = acc[mt][nt][r];
                s += v; q += v * v;
            }
            s = red16(s); q = red16(q);
            if ((lane & 15) == 0) {
                int lr = wr * 64 + qrow + mt * 16 + r;
                redS[lr * 2 + wc] = s; redQ[lr * 2 + wc] = q;
            }
        }
    __syncthreads();
    // normalize, add residual, round-2 partials
#pragma unroll
    for (int mt = 0; mt < 4; ++mt)
#pragma unroll
        for (int r = 0; r < 4; ++r) {
            int lr = wr * 64 + qrow + mt * 16 + r;
            float mu = (redS[lr * 2] + redS[lr * 2 + 1]) * (1.f / 128.f);
            float var = (redQ[lr * 2] + redQ[lr * 2 + 1]) * (1.f / 128.f) - mu * mu;
            float rs = rsqrtf(var + 1e-5f);
            size_t rbase = (size_t)(row0 + lr) * 128;
            float s2 = 0.f, q2 = 0.f;
#pragma unroll
            for (int nt = 0; nt < 4; ++nt) {
                float o = (acc[mt][nt][r] - mu) * rs * mgv[nt] + mbv[nt];
                float z = o + bf2f(h[rbase + colbase + nt * 16]);
                acc[mt][nt][r] = z;
                s2 += z; q2 += z * z;
            }
            s2 = red16(s2); q2 = red16(q2);
            if ((lane & 15) == 0) {
                redS2[lr * 2 + wc] = s2; redQ2[lr * 2 + wc] = q2;
            }
        }
    __syncthreads();
#pragma unroll
    for (int mt = 0; mt < 4; ++mt)
#pragma unroll
        for (int r = 0; r < 4; ++r) {
            int lr = wr * 64 + qrow + mt * 16 + r;
            float mu = (redS2[lr * 2] + redS2[lr * 2 + 1]) * (1.f / 128.f);
            float var = (redQ2[lr * 2] + redQ2[lr * 2 + 1]) * (1.f / 128.f) - mu * mu;
            float rs = rsqrtf(var + 1e-5f);
            size_t rbase = (size_t)(row0 + lr) * 128;
#pragma unroll
            for (int nt = 0; nt < 4; ++nt) {
                float z = acc[mt][nt][r];
                h[rbase + colbase + nt * 16] = f2bf((z - mu) * rs * egv[nt] + ebv[nt]);
            }
        }
}

// ---------------- fused attention: block = (q-tile of 32, graph); 8 waves = 4 heads x 2 subtiles ----------------

__global__ __launch_bounds__(512) void attn_k(const u16* __restrict__ qkv,
                                              const u16* __restrict__ vT,
                                              const float* __restrict__ mat,
                                              u16* __restrict__ ctx) {
    __shared__ __align__(16) u16 P[8 * 16 * 264];   // 67584 B -> 2 blocks/CU
    int t = threadIdx.x, lane = t & 63, w = t >> 6;
    int qt = blockIdx.x, b = blockIdx.y;
    int hh = w & 3, qsub = w >> 2;
    int nbase = b * LL;
    int qrow_l = qt * 32 + qsub * 16;

    const u16* qsrc = qkv + (size_t)(nbase + qrow_l + (lane & 15)) * 768 + hh * 64 + ((lane >> 4) << 3);
    bf16x8 aq0 = *(const bf16x8*)(qsrc);
    bf16x8 aq1 = *(const bf16x8*)(qsrc + 32);

    const u16* kbase = qkv + (size_t)nbase * 768 + 256 + hh * 64 + ((lane >> 4) << 3);
    f32x4 zero = {0.f, 0.f, 0.f, 0.f};
    f32x4 sc[16];
#pragma unroll
    for (int nt = 0; nt < 16; ++nt) {
        const u16* ks = kbase + (size_t)(nt * 16 + (lane & 15)) * 768;
        bf16x8 k0 = *(const bf16x8*)(ks);
        bf16x8 k1 = *(const bf16x8*)(ks + 32);
        f32x4 a = __builtin_amdgcn_mfma_f32_16x16x32_bf16(aq0, k0, zero, 0, 0, 0);
        a = __builtin_amdgcn_mfma_f32_16x16x32_bf16(aq1, k1, a, 0, 0, 0);
        sc[nt] = a;
    }

    int rloc = (lane >> 4) << 2;
    const float* mrow = mat + ((size_t)b * LL + qrow_l + rloc) * LL;
#pragma unroll
    for (int nt = 0; nt < 16; ++nt) {
        int col = nt * 16 + (lane & 15);
#pragma unroll
        for (int r = 0; r < 4; ++r)
            sc[nt][r] *= 0.125f * mrow[r * LL + col];
    }

    float mx[4] = {-1e30f, -1e30f, -1e30f, -1e30f};
#pragma unroll
    for (int nt = 0; nt < 16; ++nt)
#pragma unroll
        for (int r = 0; r < 4; ++r) mx[r] = fmaxf(mx[r], sc[nt][r]);
#pragma unroll
    for (int off = 1; off < 16; off <<= 1)
#pragma unroll
        for (int r = 0; r < 4; ++r) mx[r] = fmaxf(mx[r], __shfl_xor(mx[r], off, 64));
    float sm[4] = {0.f, 0.f, 0.f, 0.f};
#pragma unroll
    for (int nt = 0; nt < 16; ++nt)
#pragma unroll
        for (int r = 0; r < 4; ++r) {
            float e = __expf(sc[nt][r] - mx[r]);
            sc[nt][r] = e;
            sm[r] += e;
        }
#pragma unroll
    for (int off = 1; off < 16; off <<= 1)
#pragma unroll
        for (int r = 0; r < 4; ++r) sm[r] += __shfl_xor(sm[r], off, 64);
    float inv[4];
#pragma unroll
    for (int r = 0; r < 4; ++r) inv[r] = 1.f / sm[r];

    u16* Pw = P + w * (16 * 264);
#pragma unroll
    for (int nt = 0; nt < 16; ++nt)
#pragma unroll
        for (int r = 0; r < 4; ++r)
            Pw[(rloc + r) * 264 + nt * 16 + (lane & 15)] = f2bf(sc[nt][r] * inv[r]);

    const u16* vbase = vT + (size_t)(b * 4 + hh) * 16384;
    f32x4 oa[4];
#pragma unroll
    for (int dt = 0; dt < 4; ++dt) oa[dt] = zero;
#pragma unroll
    for (int kt = 0; kt < 8; ++kt) {
        bf16x8 pa = *(const bf16x8*)(Pw + (lane & 15) * 264 + kt * 32 + ((lane >> 4) << 3));
#pragma unroll
        for (int dt = 0; dt < 4; ++dt) {
            bf16x8 bv = *(const bf16x8*)(vbase + (size_t)(dt * 16 + (lane & 15)) * 256 + kt * 32 + ((lane >> 4) << 3));
            oa[dt] = __builtin_amdgcn_mfma_f32_16x16x32_bf16(pa, bv, oa[dt], 0, 0, 0);
        }
    }
#pragma unroll
    for (int dt = 0; dt < 4; ++dt)
#pragma unroll
        for (int r = 0; r < 4; ++r)
            ctx[(size_t)(nbase + qrow_l + rloc + r) * 256 + hh * 64 + dt * 16 + (lane & 15)] = f2bf(oa[dt][r]);
}

// ---------------- host launch ----------------

extern "C" void kernel_launch(void* const* d_in, const int* in_sizes, int n_in,
                              void* d_out, int out_size, void* d_ws, size_t ws_size,
                              hipStream_t stream) {
    (void)out_size; (void)ws_size; (void)n_in;
    const float* x        = (const float*)d_in[0];
    const int*   ei       = (const int*)d_in[1];
    const float* ea       = (const float*)d_in[2];
    const float* adj      = (const float*)d_in[3];
    const float* dis      = (const float*)d_in[4];
    int pb = (in_sizes[5] == 5120) ? 5 : 6;
    const float* g0_rel_w = (const float*)d_in[pb + 0];
    const float* g0_rel_b = (const float*)d_in[pb + 1];
    const float* g0_root_w= (const float*)d_in[pb + 2];
    const float* g_rel_w  = (const float*)d_in[pb + 3];
    const float* g_rel_b  = (const float*)d_in[pb + 4];
    const float* g_root_w = (const float*)d_in[pb + 5];
    const float* nm_g     = (const float*)d_in[pb + 6];
    const float* nm_b     = (const float*)d_in[pb + 7];
    const float* wq       = (const float*)d_in[pb + 8];
    const float* wk       = (const float*)d_in[pb + 9];
    const float* wv       = (const float*)d_in[pb + 10];
    const float* fc       = (const float*)d_in[pb + 11];
    const float* mha_g    = (const float*)d_in[pb + 12];
    const float* mha_b    = (const float*)d_in[pb + 13];
    const float* enc_g    = (const float*)d_in[pb + 14];
    const float* enc_b    = (const float*)d_in[pb + 15];
    const float* proj_w   = (const float*)d_in[pb + 16];
    const float* proj_b   = (const float*)d_in[pb + 17];
    const int* srcI = ei;
    const int* dstI = ei + EDGES;

    char* w = (char*)d_ws;
    float* Wf     = (float*)w; w += (size_t)33554432;   // W f32 scatter, then reused as `mat`
    u16*   Acat   = (u16*)w;   w += (size_t)16777216;   // ctx aliases this
    u16*   h      = (u16*)w;   w += (size_t)8388608;
    u16*   qkv    = (u16*)w;   w += (size_t)50331648;
    u16*   Wb     = (u16*)w;   w += (size_t)16777216;   // W bf16 [128][256][256]
    u16*   bigT   = (u16*)w;   w += (size_t)16777216;   // hT (first 8.4MB) / vT (16.7MB), temporally disjoint
    u16* wconvT0  = (u16*)w;   w += (size_t)32768;
    u16* wconvT   = (u16*)w;   w += (size_t)196608;
    u16* wqkvT    = (u16*)w;   w += (size_t)786432;
    u16* fcT      = (u16*)w;   w += (size_t)262144;
    u16* projT    = (u16*)w;   w += (size_t)32768;
    float* mat = Wf;
    u16*   ctx = Acat;
    u16*   hT  = bigT;
    u16*   vT  = bigT;

    // --- prep ---
    zero_f32<<<32768, 256, 0, stream>>>(Wf, 8388608);
    scatter_w_k<<<2048, 256, 0, stream>>>(srcI, dstI, ea, Wf);
    cast_w_k<<<8192, 256, 0, stream>>>(Wf, Wb);
    build_matrix_k<<<32768, 256, 0, stream>>>(adj, dis, mat, NB * LL * LL);

    build_wconvT0_k<<<64, 256, 0, stream>>>(g0_rel_w, g0_root_w, wconvT0);
    for (int i = 0; i < 3; ++i)
        build_wconvT_k<<<128, 256, 0, stream>>>(g_rel_w + i * 16384, g_root_w + i * 16384,
                                                wconvT + i * 32768);
    for (int i = 0; i < 4; ++i)
        build_wqkvT_k<<<384, 256, 0, stream>>>(wq + i * 32768, wk + i * 32768, wv + i * 32768,
                                               wqkvT + i * 98304);
    for (int i = 0; i < 4; ++i)
        transpose_cast_k<<<128, 256, 0, stream>>>(fc + i * 32768, fcT + i * 32768, 256, 128);
    transpose_cast_k<<<64, 256, 0, stream>>>(proj_w, projT, 128, 128);

    for (int L = 0; L < 4; ++L) {
        if (L == 0) {
            transpose_h_k<true><<<2048, 256, 0, stream>>>(h, x, hT);
            gemm_agg<true><<<256, 256, 0, stream>>>(Wb, hT, h, x, Acat);
            gemm_conv_ln<128><<<256, 256, 0, stream>>>(Acat, wconvT0, g0_rel_b,
                                                       nm_g, nm_b, h);
        } else {
            transpose_h_k<false><<<2048, 256, 0, stream>>>(h, x, hT);
            gemm_agg<false><<<256, 256, 0, stream>>>(Wb, hT, h, x, Acat);
            gemm_conv_ln<256><<<256, 256, 0, stream>>>(Acat, wconvT + (L - 1) * 32768,
                                                       g_rel_b + (L - 1) * 128,
                                                       nm_g + L * 128, nm_b + L * 128, h);
        }
        gemm_bt<1><<<dim3(256, 6), 256, 0, stream>>>(h, wqkvT + L * 98304, (void*)qkv, nullptr, 128, 768);
        vT_k<<<512, 256, 0, stream>>>(qkv, vT);
        attn_k<<<dim3(8, NB), 512, 0, stream>>>(qkv, vT, mat, ctx);
        gemm_fc_ln2<<<256, 256, 0, stream>>>(ctx, fcT + L * 32768,
                                             mha_g + L * 128, mha_b + L * 128,
                                             enc_g + L * 128, enc_b + L * 128, h);
    }
    gemm_bt<2><<<dim3(256, 1), 256, 0, stream>>>(h, projT, d_out, proj_b, 128, 128);
}

// Round 6
// 660.809 us; speedup vs baseline: 1.0742x; 1.0742x over previous
//
#include <hip/hip_runtime.h>
#include <stdint.h>

typedef unsigned short u16;
typedef unsigned int u32;
typedef __attribute__((ext_vector_type(4))) float f32x4;
typedef __attribute__((ext_vector_type(8))) short bf16x8;

#define NB 128      // graphs
#define LL 256      // nodes per graph
#define DD 128      // hidden
#define EDGES 524288
#define EPG 4096    // edges per graph
#define NN (NB*LL)

__device__ __forceinline__ float bf2f(u16 u) {
    union { u32 i; float f; } v; v.i = ((u32)u) << 16; return v.f;
}
__device__ __forceinline__ u16 f2bf(float f) {
    union { float f; u32 i; } v; v.f = f;
    u32 i = v.i;
    u32 r = (i + 0x7fffu + ((i >> 16) & 1u)) >> 16;   // RNE
    return (u16)r;
}
__device__ __forceinline__ float matfn(float a, float dv) {
    if (a != 0.f) return (a == 1.2f) ? 1.1f : a;
    return (dv == 0.f) ? 0.f : exp2f((1.f - dv) * 0.5849625007211562f); // 1.5^(1-dis)
}
__device__ __forceinline__ float red16(float v) {
#pragma unroll
    for (int off = 1; off < 16; off <<= 1) v += __shfl_xor(v, off, 64);
    return v;
}

// ---------------- prep kernels ----------------

__global__ __launch_bounds__(256) void build_matrix_k(const float* __restrict__ adj,
                                                      const float* __restrict__ dis,
                                                      float* __restrict__ mat, int n) {
    int i = blockIdx.x * 256 + threadIdx.x;
    if (i >= n) return;
    mat[i] = matfn(adj[i], dis[i]);
}

__global__ __launch_bounds__(256) void zero_f32(float* __restrict__ p, int n) {
    int i = blockIdx.x * 256 + threadIdx.x;
    if (i < n) p[i] = 0.f;
}

__global__ __launch_bounds__(256) void scatter_w_k(const int* __restrict__ srcI,
                                                   const int* __restrict__ dstI,
                                                   const float* __restrict__ ew,
                                                   float* __restrict__ Wf) {
    int e = blockIdx.x * 256 + threadIdx.x;
    if (e >= EDGES) return;
    int b = e >> 12;
    atomicAdd(&Wf[(size_t)b * 65536 + (size_t)(dstI[e] & 255) * 256 + (srcI[e] & 255)], ew[e]);
}

__global__ __launch_bounds__(256) void cast_w_k(const float* __restrict__ Wf, u16* __restrict__ Wb) {
    int i = blockIdx.x * 256 + threadIdx.x;
    float4 v = ((const float4*)Wf)[i];
    ushort4 o;
    o.x = f2bf(v.x); o.y = f2bf(v.y); o.z = f2bf(v.z); o.w = f2bf(v.w);
    ((ushort4*)Wb)[i] = o;
}

__global__ __launch_bounds__(256) void build_wconvT0_k(const float* __restrict__ rel,
                                                       const float* __restrict__ root,
                                                       u16* __restrict__ dst) {
    int i = blockIdx.x * 256 + threadIdx.x;   // 128*128
    int m = i >> 7, k = i & 127;
    float v = 0.f;
    if (k < 40) v = rel[k * 128 + m];
    else if (k >= 64 && k < 104) v = root[(k - 64) * 128 + m];
    dst[m * 128 + k] = f2bf(v);
}

__global__ __launch_bounds__(256) void build_wconvT_k(const float* __restrict__ rel,
                                                      const float* __restrict__ root,
                                                      u16* __restrict__ dst) {
    int i = blockIdx.x * 256 + threadIdx.x;   // 128*256
    int m = i >> 8, k = i & 255;
    float v = (k < 128) ? rel[k * 128 + m] : root[(k - 128) * 128 + m];
    dst[m * 256 + k] = f2bf(v);
}

__global__ __launch_bounds__(256) void build_wqkvT_k(const float* __restrict__ wq,
                                                     const float* __restrict__ wk,
                                                     const float* __restrict__ wv,
                                                     u16* __restrict__ dst) {
    int i = blockIdx.x * 256 + threadIdx.x;   // 768*128
    int m = i >> 7, k = i & 127;
    const float* s = (m < 256) ? wq : (m < 512) ? wk : wv;
    int mm = m & 255;
    dst[m * 128 + k] = f2bf(s[k * 256 + mm]);
}

__global__ __launch_bounds__(256) void transpose_cast_k(const float* __restrict__ src,
                                                        u16* __restrict__ dst, int K, int M) {
    int i = blockIdx.x * 256 + threadIdx.x;
    if (i >= K * M) return;
    int m = i / K, k = i - m * K;
    dst[i] = f2bf(src[k * M + m]);   // dst [M][K]
}

// per-graph transpose: h [N,128] bf16 (or x [N,40] f32, zero-padded) -> hT [b][128][256]
template<bool IS0>
__global__ __launch_bounds__(256) void transpose_h_k(const u16* __restrict__ h,
                                                     const float* __restrict__ x,
                                                     u16* __restrict__ hT) {
    int gw = blockIdx.x * 4 + (threadIdx.x >> 6);
    int lane = threadIdx.x & 63;
    int b = gw >> 6, rem = gw & 63, db = rem >> 5, jb = rem & 31;
    int d = (db << 6) + lane;
    u16 vals[8];
#pragma unroll
    for (int jj = 0; jj < 8; ++jj) {
        int node = (b << 8) + (jb << 3) + jj;
        if (IS0) vals[jj] = (d < 40) ? f2bf(x[(size_t)node * 40 + d]) : (u16)0;
        else     vals[jj] = h[(size_t)node * 128 + d];
    }
    *(uint4*)(hT + (size_t)b * 32768 + (size_t)d * 256 + (jb << 3)) = *(uint4*)vals;
}

// ---------------- per-graph aggregation GEMM: Acat = [W@h | h]  (K=256) ----------------

template<bool IS0>
__global__ __launch_bounds__(256) void gemm_agg(const u16* __restrict__ Wb,
                                                const u16* __restrict__ BT0,
                                                const u16* __restrict__ h,
                                                const float* __restrict__ x,
                                                u16* __restrict__ Acat) {
    __shared__ __align__(16) u16 lds[8192];
    char* ldsc = (char*)lds;
    int t = threadIdx.x, lane = t & 63, wid = t >> 6;
    int b = blockIdx.x >> 1, rt = blockIdx.x & 1;
    int row0 = rt << 7, nbase = b << 8;
    const u16* A = Wb + (size_t)b * 65536 + (size_t)row0 * 256;
    const u16* BT = BT0 + (size_t)b * 32768;

    f32x4 zero = {0.f, 0.f, 0.f, 0.f};
    f32x4 acc[4][4];
#pragma unroll
    for (int mt = 0; mt < 4; ++mt)
#pragma unroll
        for (int nt = 0; nt < 4; ++nt) acc[mt][nt] = zero;

    int wr = wid >> 1, wc = wid & 1;
    int rA = wr * 64 + (lane & 15);
    int rB = wc * 64 + (lane & 15);
    int kch = (lane >> 4) << 4;

    for (int kt = 0; kt < 8; ++kt) {
        int kc = kt << 5;
#pragma unroll
        for (int i = 0; i < 2; ++i) {
            int off = wid * 2048 + i * 1024 + lane * 16;
            int r = off >> 6, cb = off & 63;
            __builtin_amdgcn_global_load_lds((const u32*)((const char*)A + ((size_t)r * 256 + kc) * 2 + cb),
                                             (u32*)(ldsc + wid * 2048 + i * 1024), 16, 0, 0);
            __builtin_amdgcn_global_load_lds((const u32*)((const char*)BT + ((size_t)r * 256 + kc) * 2 + cb),
                                             (u32*)(ldsc + 8192 + wid * 2048 + i * 1024), 16, 0, 0);
        }
        __syncthreads();
        bf16x8 af[4], bfr[4];
#pragma unroll
        for (int mt = 0; mt < 4; ++mt)
            af[mt] = *(const bf16x8*)(ldsc + (rA + mt * 16) * 64 + kch);
#pragma unroll
        for (int nt = 0; nt < 4; ++nt)
            bfr[nt] = *(const bf16x8*)(ldsc + 8192 + (rB + nt * 16) * 64 + kch);
#pragma unroll
        for (int mt = 0; mt < 4; ++mt)
#pragma unroll
            for (int nt = 0; nt < 4; ++nt)
                acc[mt][nt] = __builtin_amdgcn_mfma_f32_16x16x32_bf16(af[mt], bfr[nt], acc[mt][nt], 0, 0, 0);
        __syncthreads();
    }

    int colb = wc * 64 + (lane & 15);
    int rowb = wr * 64 + ((lane >> 4) << 2);
#pragma unroll
    for (int mt = 0; mt < 4; ++mt)
#pragma unroll
        for (int nt = 0; nt < 4; ++nt)
#pragma unroll
            for (int r = 0; r < 4; ++r) {
                int i = rowb + mt * 16 + r;
                int c = colb + nt * 16;
                float v = acc[mt][nt][r];
                if (IS0) Acat[(size_t)(nbase + row0 + i) * 128 + c] = f2bf(v);
                else     Acat[(size_t)(nbase + row0 + i) * 256 + c] = f2bf(v);
            }
    if (IS0) {
        for (int idx = t; idx < 128 * 40; idx += 256) {
            int i = idx / 40, c = idx - i * 40;
            int node = nbase + row0 + i;
            Acat[(size_t)node * 128 + 64 + c] = f2bf(x[(size_t)node * 40 + c]);
        }
    } else {
        for (int idx = t; idx < 2048; idx += 256) {
            int i = idx >> 4, q = idx & 15;
            int node = nbase + row0 + i;
            *(uint4*)(Acat + (size_t)node * 256 + 128 + (q << 3)) =
                *(const uint4*)(h + (size_t)node * 128 + (q << 3));
        }
    }
}

// ---------------- qkv GEMM (K=128, Mtot=768) with fused V->vT transpose epilogue ----------------

__global__ __launch_bounds__(256) void gemm_qkv(const u16* __restrict__ A,
                                                const u16* __restrict__ BT,
                                                u16* __restrict__ qkv,
                                                u16* __restrict__ vT) {
    __shared__ __align__(16) u16 lds[8192];
    char* ldsc = (char*)lds;
    int t = threadIdx.x, lane = t & 63, wid = t >> 6;
    int row0 = blockIdx.x * 128, col0 = blockIdx.y * 128;

    f32x4 zero = {0.f, 0.f, 0.f, 0.f};
    f32x4 acc[4][4];
#pragma unroll
    for (int mt = 0; mt < 4; ++mt)
#pragma unroll
        for (int nt = 0; nt < 4; ++nt) acc[mt][nt] = zero;

    int wr = wid >> 1, wc = wid & 1;
    int rA = wr * 64 + (lane & 15);
    int rB = wc * 64 + (lane & 15);
    int kch = (lane >> 4) << 4;

    for (int kt = 0; kt < 4; ++kt) {
        int kc = kt << 5;
#pragma unroll
        for (int i = 0; i < 2; ++i) {
            int off = wid * 2048 + i * 1024 + lane * 16;
            int r = off >> 6, cb = off & 63;
            __builtin_amdgcn_global_load_lds((const u32*)((const char*)A + ((size_t)(row0 + r) * 128 + kc) * 2 + cb),
                                             (u32*)(ldsc + wid * 2048 + i * 1024), 16, 0, 0);
            __builtin_amdgcn_global_load_lds((const u32*)((const char*)BT + ((size_t)(col0 + r) * 128 + kc) * 2 + cb),
                                             (u32*)(ldsc + 8192 + wid * 2048 + i * 1024), 16, 0, 0);
        }
        __syncthreads();
        bf16x8 af[4], bfr[4];
#pragma unroll
        for (int mt = 0; mt < 4; ++mt)
            af[mt] = *(const bf16x8*)(ldsc + (rA + mt * 16) * 64 + kch);
#pragma unroll
        for (int nt = 0; nt < 4; ++nt)
            bfr[nt] = *(const bf16x8*)(ldsc + 8192 + (rB + nt * 16) * 64 + kch);
#pragma unroll
        for (int mt = 0; mt < 4; ++mt)
#pragma unroll
            for (int nt = 0; nt < 4; ++nt)
                acc[mt][nt] = __builtin_amdgcn_mfma_f32_16x16x32_bf16(af[mt], bfr[nt], acc[mt][nt], 0, 0, 0);
        __syncthreads();
    }

    int colb = col0 + wc * 64 + (lane & 15);
    int rowb = row0 + wr * 64 + ((lane >> 4) << 2);
    if (col0 < 512) {
        // Q/K region: normal bf16 store into qkv
#pragma unroll
        for (int mt = 0; mt < 4; ++mt)
#pragma unroll
            for (int nt = 0; nt < 4; ++nt)
#pragma unroll
                for (int r = 0; r < 4; ++r)
                    qkv[(size_t)(rowb + mt * 16 + r) * 768 + colb + nt * 16] = f2bf(acc[mt][nt][r]);
    } else {
        // V region: write transposed into vT[b*4+hh][d][node]
        int bb = row0 >> 8;
#pragma unroll
        for (int mt = 0; mt < 4; ++mt) {
            int node0 = (rowb + mt * 16) & 255;
#pragma unroll
            for (int nt = 0; nt < 4; ++nt) {
                int c = colb + nt * 16 - 512;
                int hh = c >> 6, d = c & 63;
                u16 tmp[4];
#pragma unroll
                for (int r = 0; r < 4; ++r) tmp[r] = f2bf(acc[mt][nt][r]);
                *(ushort4*)(vT + (size_t)(bb * 4 + hh) * 16384 + d * 256 + node0) = *(ushort4*)tmp;
            }
        }
    }
}

// ---------------- final projection GEMM (K=128, f32 out + bias) ----------------

__global__ __launch_bounds__(256) void gemm_proj(const u16* __restrict__ A,
                                                 const u16* __restrict__ BT,
                                                 float* __restrict__ Out,
                                                 const float* __restrict__ bias) {
    __shared__ __align__(16) u16 lds[8192];
    char* ldsc = (char*)lds;
    int t = threadIdx.x, lane = t & 63, wid = t >> 6;
    int row0 = blockIdx.x * 128;

    f32x4 zero = {0.f, 0.f, 0.f, 0.f};
    f32x4 acc[4][4];
#pragma unroll
    for (int mt = 0; mt < 4; ++mt)
#pragma unroll
        for (int nt = 0; nt < 4; ++nt) acc[mt][nt] = zero;

    int wr = wid >> 1, wc = wid & 1;
    int rA = wr * 64 + (lane & 15);
    int rB = wc * 64 + (lane & 15);
    int kch = (lane >> 4) << 4;

    for (int kt = 0; kt < 4; ++kt) {
        int kc = kt << 5;
#pragma unroll
        for (int i = 0; i < 2; ++i) {
            int off = wid * 2048 + i * 1024 + lane * 16;
            int r = off >> 6, cb = off & 63;
            __builtin_amdgcn_global_load_lds((const u32*)((const char*)A + ((size_t)(row0 + r) * 128 + kc) * 2 + cb),
                                             (u32*)(ldsc + wid * 2048 + i * 1024), 16, 0, 0);
            __builtin_amdgcn_global_load_lds((const u32*)((const char*)BT + ((size_t)r * 128 + kc) * 2 + cb),
                                             (u32*)(ldsc + 8192 + wid * 2048 + i * 1024), 16, 0, 0);
        }
        __syncthreads();
        bf16x8 af[4], bfr[4];
#pragma unroll
        for (int mt = 0; mt < 4; ++mt)
            af[mt] = *(const bf16x8*)(ldsc + (rA + mt * 16) * 64 + kch);
#pragma unroll
        for (int nt = 0; nt < 4; ++nt)
            bfr[nt] = *(const bf16x8*)(ldsc + 8192 + (rB + nt * 16) * 64 + kch);
#pragma unroll
        for (int mt = 0; mt < 4; ++mt)
#pragma unroll
            for (int nt = 0; nt < 4; ++nt)
                acc[mt][nt] = __builtin_amdgcn_mfma_f32_16x16x32_bf16(af[mt], bfr[nt], acc[mt][nt], 0, 0, 0);
        __syncthreads();
    }

    int colb = wc * 64 + (lane & 15);
    int rowb = row0 + wr * 64 + ((lane >> 4) << 2);
#pragma unroll
    for (int mt = 0; mt < 4; ++mt)
#pragma unroll
        for (int nt = 0; nt < 4; ++nt)
#pragma unroll
            for (int r = 0; r < 4; ++r)
                Out[(size_t)(rowb + mt * 16 + r) * 128 + colb + nt * 16] =
                    acc[mt][nt][r] + bias[colb + nt * 16];
}

// ---------------- conv GEMM with fused bias + LN + relu (Mtot = 128 full width) ----------------

template<int KK>
__global__ __launch_bounds__(256) void gemm_conv_ln(const u16* __restrict__ A,
                                                    const u16* __restrict__ BT,
                                                    const float* __restrict__ rb,
                                                    const float* __restrict__ g,
                                                    const float* __restrict__ be,
                                                    u16* __restrict__ hout) {
    __shared__ __align__(16) u16 lds[8192];
    char* ldsc = (char*)lds;
    int t = threadIdx.x, lane = t & 63, wid = t >> 6;
    int row0 = blockIdx.x * 128;

    f32x4 zero = {0.f, 0.f, 0.f, 0.f};
    f32x4 acc[4][4];
#pragma unroll
    for (int mt = 0; mt < 4; ++mt)
#pragma unroll
        for (int nt = 0; nt < 4; ++nt) acc[mt][nt] = zero;

    int wr = wid >> 1, wc = wid & 1;
    int rA = wr * 64 + (lane & 15);
    int rB = wc * 64 + (lane & 15);
    int kch = (lane >> 4) << 4;

    for (int kt = 0; kt < (KK >> 5); ++kt) {
        int kc = kt << 5;
#pragma unroll
        for (int i = 0; i < 2; ++i) {
            int off = wid * 2048 + i * 1024 + lane * 16;
            int r = off >> 6, cb = off & 63;
            __builtin_amdgcn_global_load_lds((const u32*)((const char*)A + ((size_t)(row0 + r) * KK + kc) * 2 + cb),
                                             (u32*)(ldsc + wid * 2048 + i * 1024), 16, 0, 0);
            __builtin_amdgcn_global_load_lds((const u32*)((const char*)BT + ((size_t)r * KK + kc) * 2 + cb),
                                             (u32*)(ldsc + 8192 + wid * 2048 + i * 1024), 16, 0, 0);
        }
        __syncthreads();
        bf16x8 af[4], bfr[4];
#pragma unroll
        for (int mt = 0; mt < 4; ++mt)
            af[mt] = *(const bf16x8*)(ldsc + (rA + mt * 16) * 64 + kch);
#pragma unroll
        for (int nt = 0; nt < 4; ++nt)
            bfr[nt] = *(const bf16x8*)(ldsc + 8192 + (rB + nt * 16) * 64 + kch);
#pragma unroll
        for (int mt = 0; mt < 4; ++mt)
#pragma unroll
            for (int nt = 0; nt < 4; ++nt)
                acc[mt][nt] = __builtin_amdgcn_mfma_f32_16x16x32_bf16(af[mt], bfr[nt], acc[mt][nt], 0, 0, 0);
        __syncthreads();
    }

    float* redS = (float*)ldsc;            // [128][2]
    float* redQ = (float*)(ldsc + 2048);   // [128][2]
    int colbase = wc * 64 + (lane & 15);
    int qrow = (lane >> 4) << 2;
    float rbv[4], gv[4], bev[4];
#pragma unroll
    for (int nt = 0; nt < 4; ++nt) {
        int c = colbase + nt * 16;
        rbv[nt] = rb[c]; gv[nt] = g[c]; bev[nt] = be[c];
    }
#pragma unroll
    for (int mt = 0; mt < 4; ++mt)
#pragma unroll
        for (int r = 0; r < 4; ++r) {
            float s = 0.f, q = 0.f;
#pragma unroll
            for (int nt = 0; nt < 4; ++nt) {
                float v = acc[mt][nt][r] + rbv[nt];
                s += v; q += v * v;
            }
            s = red16(s); q = red16(q);
            if ((lane & 15) == 0) {
                int lr = wr * 64 + qrow + mt * 16 + r;
                redS[lr * 2 + wc] = s; redQ[lr * 2 + wc] = q;
            }
        }
    __syncthreads();
#pragma unroll
    for (int mt = 0; mt < 4; ++mt)
#pragma unroll
        for (int r = 0; r < 4; ++r) {
            int lr = wr * 64 + qrow + mt * 16 + r;
            float mu = (redS[lr * 2] + redS[lr * 2 + 1]) * (1.f / 128.f);
            float var = (redQ[lr * 2] + redQ[lr * 2 + 1]) * (1.f / 128.f) - mu * mu;
            float rs = rsqrtf(var + 1e-5f);
            size_t rbase = (size_t)(row0 + lr) * 128;
#pragma unroll
            for (int nt = 0; nt < 4; ++nt) {
                float v = acc[mt][nt][r] + rbv[nt];
                float o = (v - mu) * rs * gv[nt] + bev[nt];
                o = o < 0.f ? 0.f : o;
                hout[rbase + colbase + nt * 16] = f2bf(o);
            }
        }
}

// ---------------- fc GEMM with fused LN -> +residual -> LN (K=256, Mtot=128) ----------------

__global__ __launch_bounds__(256) void gemm_fc_ln2(const u16* __restrict__ A,
                                                   const u16* __restrict__ BT,
                                                   const float* __restrict__ mg,
                                                   const float* __restrict__ mb,
                                                   const float* __restrict__ eg,
                                                   const float* __restrict__ eb,
                                                   u16* __restrict__ h) {
    __shared__ __align__(16) u16 lds[8192];
    char* ldsc = (char*)lds;
    int t = threadIdx.x, lane = t & 63, wid = t >> 6;
    int row0 = blockIdx.x * 128;

    f32x4 zero = {0.f, 0.f, 0.f, 0.f};
    f32x4 acc[4][4];
#pragma unroll
    for (int mt = 0; mt < 4; ++mt)
#pragma unroll
        for (int nt = 0; nt < 4; ++nt) acc[mt][nt] = zero;

    int wr = wid >> 1, wc = wid & 1;
    int rA = wr * 64 + (lane & 15);
    int rB = wc * 64 + (lane & 15);
    int kch = (lane >> 4) << 4;

    for (int kt = 0; kt < 8; ++kt) {
        int kc = kt << 5;
#pragma unroll
        for (int i = 0; i < 2; ++i) {
            int off = wid * 2048 + i * 1024 + lane * 16;
            int r = off >> 6, cb = off & 63;
            __builtin_amdgcn_global_load_lds((const u32*)((const char*)A + ((size_t)(row0 + r) * 256 + kc) * 2 + cb),
                                             (u32*)(ldsc + wid * 2048 + i * 1024), 16, 0, 0);
            __builtin_amdgcn_global_load_lds((const u32*)((const char*)BT + ((size_t)r * 256 + kc) * 2 + cb),
                                             (u32*)(ldsc + 8192 + wid * 2048 + i * 1024), 16, 0, 0);
        }
        __syncthreads();
        bf16x8 af[4], bfr[4];
#pragma unroll
        for (int mt = 0; mt < 4; ++mt)
            af[mt] = *(const bf16x8*)(ldsc + (rA + mt * 16) * 64 + kch);
#pragma unroll
        for (int nt = 0; nt < 4; ++nt)
            bfr[nt] = *(const bf16x8*)(ldsc + 8192 + (rB + nt * 16) * 64 + kch);
#pragma unroll
        for (int mt = 0; mt < 4; ++mt)
#pragma unroll
            for (int nt = 0; nt < 4; ++nt)
                acc[mt][nt] = __builtin_amdgcn_mfma_f32_16x16x32_bf16(af[mt], bfr[nt], acc[mt][nt], 0, 0, 0);
        __syncthreads();
    }

    float* redS  = (float*)ldsc;
    float* redQ  = (float*)(ldsc + 2048);
    float* redS2 = (float*)(ldsc + 4096);
    float* redQ2 = (float*)(ldsc + 6144);
    int colbase = wc * 64 + (lane & 15);
    int qrow = (lane >> 4) << 2;
    float mgv[4], mbv[4], egv[4], ebv[4];
#pragma unroll
    for (int nt = 0; nt < 4; ++nt) {
        int c = colbase + nt * 16;
        mgv[nt] = mg[c]; mbv[nt] = mb[c]; egv[nt] = eg[c]; ebv[nt] = eb[c];
    }
#pragma unroll
    for (int mt = 0; mt < 4; ++mt)
#pragma unroll
        for (int r = 0; r < 4; ++r) {
            float s = 0.f, q = 0.f;
#pragma unroll
            for (int nt = 0; nt < 4; ++nt) {
                float v = acc[mt][nt][r];
                s += v; q += v * v;
            }
            s = red16(s); q = red16(q);
            if ((lane & 15) == 0) {
                int lr = wr * 64 + qrow + mt * 16 + r;
                redS[lr * 2 + wc] = s; redQ[lr * 2 + wc] = q;
            }
        }
    __syncthreads();
#pragma unroll
    for (int mt = 0; mt < 4; ++mt)
#pragma unroll
        for (int r = 0; r < 4; ++r) {
            int lr = wr * 64 + qrow + mt * 16 + r;
            float mu = (redS[lr * 2] + redS[lr * 2 + 1]) * (1.f / 128.f);
            float var = (redQ[lr * 2] + redQ[lr * 2 + 1]) * (1.f / 128.f) - mu * mu;
            float rs = rsqrtf(var + 1e-5f);
            size_t rbase = (size_t)(row0 + lr) * 128;
            float s2 = 0.f, q2 = 0.f;
#pragma unroll
            for (int nt = 0; nt < 4; ++nt) {
                float o = (acc[mt][nt][r] - mu) * rs * mgv[nt] + mbv[nt];
                float z = o + bf2f(h[rbase + colbase + nt * 16]);
                acc[mt][nt][r] = z;
                s2 += z; q2 += z * z;
            }
            s2 = red16(s2); q2 = red16(q2);
            if ((lane & 15) == 0) {
                redS2[lr * 2 + wc] = s2; redQ2[lr * 2 + wc] = q2;
            }
        }
    __syncthreads();
#pragma unroll
    for (int mt = 0; mt < 4; ++mt)
#pragma unroll
        for (int r = 0; r < 4; ++r) {
            int lr = wr * 64 + qrow + mt * 16 + r;
            float mu = (redS2[lr * 2] + redS2[lr * 2 + 1]) * (1.f / 128.f);
            float var = (redQ2[lr * 2] + redQ2[lr * 2 + 1]) * (1.f / 128.f) - mu * mu;
            float rs = rsqrtf(var + 1e-5f);
            size_t rbase = (size_t)(row0 + lr) * 128;
#pragma unroll
            for (int nt = 0; nt < 4; ++nt) {
                float z = acc[mt][nt][r];
                h[rbase + colbase + nt * 16] = f2bf((z - mu) * rs * egv[nt] + ebv[nt]);
            }
        }
}

// ---------------- fused attention: grid (b, qt) so same-graph blocks share an XCD L2 ----------------

__global__ __launch_bounds__(512) void attn_k(const u16* __restrict__ qkv,
                                              const u16* __restrict__ vT,
                                              const float* __restrict__ mat,
                                              u16* __restrict__ ctx) {
    __shared__ __align__(16) u16 P[8 * 16 * 264];   // 67584 B -> 2 blocks/CU
    int t = threadIdx.x, lane = t & 63, w = t >> 6;
    int b = blockIdx.x, qt = blockIdx.y;            // b fast-varying -> wgid%8 == b%8 -> same XCD per graph
    int hh = w & 3, qsub = w >> 2;
    int nbase = b * LL;
    int qrow_l = qt * 32 + qsub * 16;

    const u16* qsrc = qkv + (size_t)(nbase + qrow_l + (lane & 15)) * 768 + hh * 64 + ((lane >> 4) << 3);
    bf16x8 aq0 = *(const bf16x8*)(qsrc);
    bf16x8 aq1 = *(const bf16x8*)(qsrc + 32);

    const u16* kbase = qkv + (size_t)nbase * 768 + 256 + hh * 64 + ((lane >> 4) << 3);
    f32x4 zero = {0.f, 0.f, 0.f, 0.f};
    f32x4 sc[16];
#pragma unroll
    for (int nt = 0; nt < 16; ++nt) {
        const u16* ks = kbase + (size_t)(nt * 16 + (lane & 15)) * 768;
        bf16x8 k0 = *(const bf16x8*)(ks);
        bf16x8 k1 = *(const bf16x8*)(ks + 32);
        f32x4 a = __builtin_amdgcn_mfma_f32_16x16x32_bf16(aq0, k0, zero, 0, 0, 0);
        a = __builtin_amdgcn_mfma_f32_16x16x32_bf16(aq1, k1, a, 0, 0, 0);
        sc[nt] = a;
    }

    int rloc = (lane >> 4) << 2;
    const float* mrow = mat + ((size_t)b * LL + qrow_l + rloc) * LL;
#pragma unroll
    for (int nt = 0; nt < 16; ++nt) {
        int col = nt * 16 + (lane & 15);
#pragma unroll
        for (int r = 0; r < 4; ++r)
            sc[nt][r] *= 0.125f * mrow[r * LL + col];
    }

    float mx[4] = {-1e30f, -1e30f, -1e30f, -1e30f};
#pragma unroll
    for (int nt = 0; nt < 16; ++nt)
#pragma unroll
        for (int r = 0; r < 4; ++r) mx[r] = fmaxf(mx[r], sc[nt][r]);
#pragma unroll
    for (int off = 1; off < 16; off <<= 1)
#pragma unroll
        for (int r = 0; r < 4; ++r) mx[r] = fmaxf(mx[r], __shfl_xor(mx[r], off, 64));
    float sm[4] = {0.f, 0.f, 0.f, 0.f};
#pragma unroll
    for (int nt = 0; nt < 16; ++nt)
#pragma unroll
        for (int r = 0; r < 4; ++r) {
            float e = __expf(sc[nt][r] - mx[r]);
            sc[nt][r] = e;
            sm[r] += e;
        }
#pragma unroll
    for (int off = 1; off < 16; off <<= 1)
#pragma unroll
        for (int r = 0; r < 4; ++r) sm[r] += __shfl_xor(sm[r], off, 64);
    float inv[4];
#pragma unroll
    for (int r = 0; r < 4; ++r) inv[r] = 1.f / sm[r];

    u16* Pw = P + w * (16 * 264);
#pragma unroll
    for (int nt = 0; nt < 16; ++nt)
#pragma unroll
        for (int r = 0; r < 4; ++r)
            Pw[(rloc + r) * 264 + nt * 16 + (lane & 15)] = f2bf(sc[nt][r] * inv[r]);

    const u16* vbase = vT + (size_t)(b * 4 + hh) * 16384;
    f32x4 oa[4];
#pragma unroll
    for (int dt = 0; dt < 4; ++dt) oa[dt] = zero;
#pragma unroll
    for (int kt = 0; kt < 8; ++kt) {
        bf16x8 pa = *(const bf16x8*)(Pw + (lane & 15) * 264 + kt * 32 + ((lane >> 4) << 3));
#pragma unroll
        for (int dt = 0; dt < 4; ++dt) {
            bf16x8 bv = *(const bf16x8*)(vbase + (size_t)(dt * 16 + (lane & 15)) * 256 + kt * 32 + ((lane >> 4) << 3));
            oa[dt] = __builtin_amdgcn_mfma_f32_16x16x32_bf16(pa, bv, oa[dt], 0, 0, 0);
        }
    }
#pragma unroll
    for (int dt = 0; dt < 4; ++dt)
#pragma unroll
        for (int r = 0; r < 4; ++r)
            ctx[(size_t)(nbase + qrow_l + rloc + r) * 256 + hh * 64 + dt * 16 + (lane & 15)] = f2bf(oa[dt][r]);
}

// ---------------- host launch ----------------

extern "C" void kernel_launch(void* const* d_in, const int* in_sizes, int n_in,
                              void* d_out, int out_size, void* d_ws, size_t ws_size,
                              hipStream_t stream) {
    (void)out_size; (void)ws_size; (void)n_in;
    const float* x        = (const float*)d_in[0];
    const int*   ei       = (const int*)d_in[1];
    const float* ea       = (const float*)d_in[2];
    const float* adj      = (const float*)d_in[3];
    const float* dis      = (const float*)d_in[4];
    int pb = (in_sizes[5] == 5120) ? 5 : 6;
    const float* g0_rel_w = (const float*)d_in[pb + 0];
    const float* g0_rel_b = (const float*)d_in[pb + 1];
    const float* g0_root_w= (const float*)d_in[pb + 2];
    const float* g_rel_w  = (const float*)d_in[pb + 3];
    const float* g_rel_b  = (const float*)d_in[pb + 4];
    const float* g_root_w = (const float*)d_in[pb + 5];
    const float* nm_g     = (const float*)d_in[pb + 6];
    const float* nm_b     = (const float*)d_in[pb + 7];
    const float* wq       = (const float*)d_in[pb + 8];
    const float* wk       = (const float*)d_in[pb + 9];
    const float* wv       = (const float*)d_in[pb + 10];
    const float* fc       = (const float*)d_in[pb + 11];
    const float* mha_g    = (const float*)d_in[pb + 12];
    const float* mha_b    = (const float*)d_in[pb + 13];
    const float* enc_g    = (const float*)d_in[pb + 14];
    const float* enc_b    = (const float*)d_in[pb + 15];
    const float* proj_w   = (const float*)d_in[pb + 16];
    const float* proj_b   = (const float*)d_in[pb + 17];
    const int* srcI = ei;
    const int* dstI = ei + EDGES;

    char* w = (char*)d_ws;
    float* Wf     = (float*)w; w += (size_t)33554432;   // W f32 scatter, then reused as `mat`
    u16*   Acat   = (u16*)w;   w += (size_t)16777216;   // ctx aliases this
    u16*   h      = (u16*)w;   w += (size_t)8388608;
    u16*   qkv    = (u16*)w;   w += (size_t)50331648;
    u16*   Wb     = (u16*)w;   w += (size_t)16777216;   // W bf16 [128][256][256]
    u16*   bigT   = (u16*)w;   w += (size_t)16777216;   // hT (8.4MB) / vT (16.7MB), temporally disjoint
    u16* wconvT0  = (u16*)w;   w += (size_t)32768;
    u16* wconvT   = (u16*)w;   w += (size_t)196608;
    u16* wqkvT    = (u16*)w;   w += (size_t)786432;
    u16* fcT      = (u16*)w;   w += (size_t)262144;
    u16* projT    = (u16*)w;   w += (size_t)32768;
    float* mat = Wf;
    u16*   ctx = Acat;
    u16*   hT  = bigT;
    u16*   vT  = bigT;

    // --- prep ---
    zero_f32<<<32768, 256, 0, stream>>>(Wf, 8388608);
    scatter_w_k<<<2048, 256, 0, stream>>>(srcI, dstI, ea, Wf);
    cast_w_k<<<8192, 256, 0, stream>>>(Wf, Wb);
    build_matrix_k<<<32768, 256, 0, stream>>>(adj, dis, mat, NB * LL * LL);

    build_wconvT0_k<<<64, 256, 0, stream>>>(g0_rel_w, g0_root_w, wconvT0);
    for (int i = 0; i < 3; ++i)
        build_wconvT_k<<<128, 256, 0, stream>>>(g_rel_w + i * 16384, g_root_w + i * 16384,
                                                wconvT + i * 32768);
    for (int i = 0; i < 4; ++i)
        build_wqkvT_k<<<384, 256, 0, stream>>>(wq + i * 32768, wk + i * 32768, wv + i * 32768,
                                               wqkvT + i * 98304);
    for (int i = 0; i < 4; ++i)
        transpose_cast_k<<<128, 256, 0, stream>>>(fc + i * 32768, fcT + i * 32768, 256, 128);
    transpose_cast_k<<<64, 256, 0, stream>>>(proj_w, projT, 128, 128);

    for (int L = 0; L < 4; ++L) {
        if (L == 0) {
            transpose_h_k<true><<<2048, 256, 0, stream>>>(h, x, hT);
            gemm_agg<true><<<256, 256, 0, stream>>>(Wb, hT, h, x, Acat);
            gemm_conv_ln<128><<<256, 256, 0, stream>>>(Acat, wconvT0, g0_rel_b,
                                                       nm_g, nm_b, h);
        } else {
            transpose_h_k<false><<<2048, 256, 0, stream>>>(h, x, hT);
            gemm_agg<false><<<256, 256, 0, stream>>>(Wb, hT, h, x, Acat);
            gemm_conv_ln<256><<<256, 256, 0, stream>>>(Acat, wconvT + (L - 1) * 32768,
                                                       g_rel_b + (L - 1) * 128,
                                                       nm_g + L * 128, nm_b + L * 128, h);
        }
        gemm_qkv<<<dim3(256, 6), 256, 0, stream>>>(h, wqkvT + L * 98304, qkv, vT);
        attn_k<<<dim3(NB, 8), 512, 0, stream>>>(qkv, vT, mat, ctx);
        gemm_fc_ln2<<<256, 256, 0, stream>>>(ctx, fcT + L * 32768,
                                             mha_g + L * 128, mha_b + L * 128,
                                             enc_g + L * 128, enc_b + L * 128, h);
    }
    gemm_proj<<<256, 256, 0, stream>>>(h, projT, (float*)d_out, proj_b);
}